// Round 5
// baseline (511.164 us; speedup 1.0000x reference)
//
#include <hip/hip_runtime.h>
#include <math.h>

#define N_TOK 16384
#define DDIM  4096
#define NEXP  64
#define TM    32             // tokens per block
#define WINF  256            // f32 columns staged per row per step (1 KB/row)
#define NSTEP (DDIM / WINF)  // 16 steps
#define LSTR  68             // LDS logit row stride
#define TAU   1e-3f          // near-tie refine threshold

typedef __attribute__((ext_vector_type(8))) short bf16x8;
typedef __attribute__((ext_vector_type(4))) float f32x4;

// Split 8 consecutive fp32 into hi/lo bf16 (truncation split: x = hi + lo + eps).
__device__ __forceinline__ void split8(f32x4 v0, f32x4 v1, bf16x8& hi, bf16x8& lo) {
    float f[8];
    *(f32x4*)&f[0] = v0;  *(f32x4*)&f[4] = v1;
    #pragma unroll
    for (int i = 0; i < 8; ++i) {
        unsigned u  = __float_as_uint(f[i]);
        unsigned uh = u & 0xFFFF0000u;
        float    rf = f[i] - __uint_as_float(uh);
        hi[i] = (short)(u >> 16);
        lo[i] = (short)(__float_as_uint(rf) >> 16);
    }
}

// ---------------- W pre-pack: fragment-ordered bf16 hi/lo (1 MB in d_ws) -----
// Wp[((c*4+t)*2+p)*512 + lane*8 .. +7] = split of W[t*16+(lane&15)][c*32+(lane>>4)*8 + 0..7]
__global__ __launch_bounds__(256) void pack_w_kernel(
    const float* __restrict__ W, short* __restrict__ Wp)
{
    const int c    = blockIdx.x;          // K chunk of 32
    const int tid  = threadIdx.x;
    const int t    = tid >> 6;
    const int lane = tid & 63;
    const int r16  = lane & 15;
    const int koct = lane >> 4;
    const float* src = W + (size_t)(t * 16 + r16) * DDIM + c * 32 + koct * 8;
    f32x4 b0 = *(const f32x4*)src;
    f32x4 b1 = *(const f32x4*)(src + 4);
    bf16x8 hi, lo;
    split8(b0, b1, hi, lo);
    short* d = Wp + ((size_t)(c * 4 + t) * 2) * 512 + lane * 8;
    *(bf16x8*)d         = hi;
    *(bf16x8*)(d + 512) = lo;
}

// ---------------- main kernel: reg-staged double buffer, 8 uniform waves -----
// x path uses plain global_load_dwordx4 -> VGPR -> ds_write (NOT global_load_lds:
// R3/R4 measured gl2lds at ~0.4 B/cyc/wave regardless of queue depth).
// Ring: 2 buffers x 32 KB; buffer = [row 0..31][1 KB window], bytes stored
// XOR-swizzled: LDS[r][b] = x[r][win + (b ^ ((r&7)<<4))].
__global__ __launch_bounds__(512, 4) void topk_gate_kernel(
    const float* __restrict__ x, const short* __restrict__ Wp,
    const float* __restrict__ W, float* __restrict__ out)
{
    __shared__ __align__(16) char sraw[73728];   // ring 64K; Lg 69.6K; +red 4K
    __shared__ int    top_i[TM * 2];
    __shared__ float  top_w[TM * 2];
    __shared__ int    nflag;
    __shared__ int    flist[TM];
    __shared__ double lgd[NEXP];
    __shared__ int    rbi[2];
    __shared__ float  rbw[2];

    const int tid  = threadIdx.x;
    const int lane = tid & 63;
    const int w    = tid >> 6;            // wave 0..7 (uniform role)
    const int block_tok = blockIdx.x * TM;
    const int r16  = lane & 15;
    const int koct = lane >> 4;
    const int m    = (r16 & 7) << 4;      // read-side XOR
    const int o0   = w * 128 + koct * 32; // this wave's chunk offset in window

    // staging: wave w owns local rows w*4 .. w*4+3 (16384 B global row stride)
    const char* xrow = (const char*)x
                     + (size_t)(block_tok + w * 4) * (DDIM * 4) + lane * 16;
    const int sw0 = (lane * 16) ^ ((((w * 4) + 0) & 7) << 4);
    const int sw1 = (lane * 16) ^ ((((w * 4) + 1) & 7) << 4);
    const int sw2 = (lane * 16) ^ ((((w * 4) + 2) & 7) << 4);
    const int sw3 = (lane * 16) ^ ((((w * 4) + 3) & 7) << 4);
    char* const wbase = sraw + (w * 4) * 1024;

    f32x4 rA0, rA1, rA2, rA3, rB0, rB1, rB2, rB3;

#define LOADR(a0, a1, a2, a3, S) do {                                        \
    const char* _s = xrow + (size_t)(S) * 1024;                              \
    a0 = *(const f32x4*)(_s);                                                \
    a1 = *(const f32x4*)(_s + 16384);                                        \
    a2 = *(const f32x4*)(_s + 32768);                                        \
    a3 = *(const f32x4*)(_s + 49152);                                        \
} while (0)

#define WRITER(a0, a1, a2, a3, B) do {                                       \
    char* _d = wbase + (B) * 32768;                                          \
    *(f32x4*)(_d +        sw0) = a0;                                         \
    *(f32x4*)(_d + 1024 + sw1) = a1;                                         \
    *(f32x4*)(_d + 2048 + sw2) = a2;                                         \
    *(f32x4*)(_d + 3072 + sw3) = a3;                                         \
} while (0)

    f32x4 acc[2][4];
    #pragma unroll
    for (int tt = 0; tt < 2; ++tt)
        #pragma unroll
        for (int t = 0; t < 4; ++t) acc[tt][t] = (f32x4){0.f, 0.f, 0.f, 0.f};

#define COMPUTE(B, S) do {                                                   \
    const char* _buf = sraw + (B) * 32768;                                   \
    const int _cg = (S) * 8 + w;                 /* global K chunk */        \
    bf16x8 ah[2], al[2];                                                     \
    _Pragma("unroll")                                                        \
    for (int tt = 0; tt < 2; ++tt) {                                         \
        const char* xb = _buf + ((tt * 16 + r16) << 10);                     \
        f32x4 a0 = *(const f32x4*)(xb + (o0 ^ m));                           \
        f32x4 a1 = *(const f32x4*)(xb + ((o0 + 16) ^ m));                    \
        split8(a0, a1, ah[tt], al[tt]);                                      \
    }                                                                        \
    _Pragma("unroll")                                                        \
    for (int t = 0; t < 4; ++t) {                                            \
        const short* wb = Wp + ((size_t)(_cg * 4 + t) * 2) * 512 + lane * 8; \
        bf16x8 bh = *(const bf16x8*)wb;                                      \
        bf16x8 bl = *(const bf16x8*)(wb + 512);                              \
        _Pragma("unroll")                                                    \
        for (int tt = 0; tt < 2; ++tt) {                                     \
            acc[tt][t] = __builtin_amdgcn_mfma_f32_16x16x32_bf16(ah[tt], bh, acc[tt][t], 0, 0, 0); \
            acc[tt][t] = __builtin_amdgcn_mfma_f32_16x16x32_bf16(ah[tt], bl, acc[tt][t], 0, 0, 0); \
            acc[tt][t] = __builtin_amdgcn_mfma_f32_16x16x32_bf16(al[tt], bh, acc[tt][t], 0, 0, 0); \
        }                                                                    \
    }                                                                        \
} while (0)

    // ---- 2-deep reg pipeline over 16 steps, double-buffered LDS ----
    LOADR(rA0, rA1, rA2, rA3, 0);
    LOADR(rB0, rB1, rB2, rB3, 1);
    #pragma unroll 1
    for (int s = 0; s < NSTEP; s += 2) {
        WRITER(rA0, rA1, rA2, rA3, 0);          // compiler waits rA loads here
        __syncthreads();
        if (s + 2 < NSTEP) LOADR(rA0, rA1, rA2, rA3, s + 2);
        COMPUTE(0, s);
        __syncthreads();
        WRITER(rB0, rB1, rB2, rB3, 1);
        __syncthreads();
        if (s + 3 < NSTEP) LOADR(rB0, rB1, rB2, rB3, s + 3);
        COMPUTE(1, s + 1);
        __syncthreads();
    }
#undef LOADR
#undef WRITER
#undef COMPUTE

    // ---- epilogue: per-partition logits into LDS (ring dead) ----
    float* Lg = (float*)sraw;             // [8][32][LSTR]
    #pragma unroll
    for (int tt = 0; tt < 2; ++tt)
        #pragma unroll
        for (int t = 0; t < 4; ++t)
            #pragma unroll
            for (int r = 0; r < 4; ++r)
                Lg[(w * TM + tt * 16 + koct * 4 + r) * LSTR + t * 16 + r16] = acc[tt][t][r];
    if (tid == 0) nflag = 0;
    __syncthreads();

    // ---- combine 8 K-partitions: 512 threads x (1 token, 4 experts) ----
    {
        const int tok = tid >> 4;
        const int e4  = (tid & 15) * 4;
        float4 s0 = *(float4*)&Lg[(0 * TM + tok) * LSTR + e4];
        #pragma unroll
        for (int qq = 1; qq < 8; ++qq) {
            float4 v = *(float4*)&Lg[(qq * TM + tok) * LSTR + e4];
            s0.x += v.x; s0.y += v.y; s0.z += v.z; s0.w += v.w;
        }
        *(float4*)&Lg[tok * LSTR + e4] = s0;
    }
    __syncthreads();

    // ---- top-3 scan + 2-way softmax + near-tie flagging ----
    if (tid < TM) {
        float m1 = -INFINITY, m2 = -INFINITY, m3 = -INFINITY;
        int i1 = 0, i2 = 0;
        for (int e = 0; e < NEXP; ++e) {
            float v = Lg[tid * LSTR + e];
            if (v > m1)      { m3 = m2; m2 = m1; i2 = i1; m1 = v; i1 = e; }
            else if (v > m2) { m3 = m2; m2 = v; i2 = e; }
            else if (v > m3) { m3 = v; }
        }
        float d  = expf(m2 - m1);
        float rn = 1.0f / (1.0f + d);
        top_i[tid * 2 + 0] = i1;  top_i[tid * 2 + 1] = i2;
        top_w[tid * 2 + 0] = rn;  top_w[tid * 2 + 1] = d * rn;
        float2* oi = (float2*)(out + (size_t)N_TOK * NEXP);
        oi[block_tok + tid] = make_float2((float)i1, (float)i2);
        if ((m1 - m2 < TAU) || (m2 - m3 < TAU)) {
            int pp = atomicAdd(&nflag, 1);
            flist[pp] = tid;
        }
    }
    __syncthreads();

    // ---- dense weight scatter: 32 tokens x 64 experts = 512 float4 ----
    {
        float4* ow = (float4*)(out + (size_t)block_tok * NEXP);
        const int tok = tid >> 4;
        const int e4  = (tid & 15) * 4;
        int a1 = top_i[tok * 2], a2 = top_i[tok * 2 + 1];
        float v1 = top_w[tok * 2], v2 = top_w[tok * 2 + 1];
        float4 v; float* vp = (float*)&v;
        #pragma unroll
        for (int q = 0; q < 4; ++q) {
            int e = e4 + q;
            vp[q] = (e == a1) ? v1 : ((e == a2) ? v2 : 0.0f);
        }
        ow[tid] = v;
    }
    __syncthreads();

    // ---- in-block fp64 re-resolution of flagged tokens ----
    double* red = (double*)(sraw + 69632);   // past Lg
    const int fn = nflag;
    for (int f = 0; f < fn; ++f) {
        const int tok = block_tok + flist[f];
        {
            const int e = tid & 63, q = tid >> 6;   // q: 0..7
            const float* wr = W + (size_t)e * DDIM + q * (DDIM / 8);
            const float* xr = x + (size_t)tok * DDIM + q * (DDIM / 8);
            double pp = 0.0;
            for (int k = 0; k < DDIM / 8; k += 4) {
                float4 wv = *(const float4*)(wr + k);
                float4 xv = *(const float4*)(xr + k);
                pp += (double)xv.x * (double)wv.x;
                pp += (double)xv.y * (double)wv.y;
                pp += (double)xv.z * (double)wv.z;
                pp += (double)xv.w * (double)wv.w;
            }
            red[tid] = pp;
        }
        __syncthreads();
        if (tid < 64) {
            double s = 0.0;
            #pragma unroll
            for (int j = 0; j < 8; ++j) s += red[tid + 64 * j];
            lgd[tid] = s;
        }
        __syncthreads();

        if (tid == 0) {
            double m1 = -INFINITY, m2 = -INFINITY;
            int i1 = 0, i2 = 0;
            for (int ee = 0; ee < NEXP; ++ee) {
                double v = lgd[ee];
                if (v > m1)      { m2 = m1; i2 = i1; m1 = v; i1 = ee; }
                else if (v > m2) { m2 = v; i2 = ee; }
            }
            double d  = exp(m2 - m1);
            double rn = 1.0 / (1.0 + d);
            rbi[0] = i1; rbi[1] = i2;
            rbw[0] = (float)rn; rbw[1] = (float)(d * rn);
            float2* oi = (float2*)(out + (size_t)N_TOK * NEXP);
            oi[tok] = make_float2((float)i1, (float)i2);
        }
        __syncthreads();

        if (tid < 16) {
            float4 v = make_float4(0.f, 0.f, 0.f, 0.f);
            float* vp = (float*)&v;
            #pragma unroll
            for (int qq = 0; qq < 4; ++qq) {
                int ee = tid * 4 + qq;
                if (ee == rbi[0]) vp[qq] = rbw[0];
                else if (ee == rbi[1]) vp[qq] = rbw[1];
            }
            ((float4*)(out + (size_t)tok * NEXP))[tid] = v;
        }
        __syncthreads();
    }
}

extern "C" void kernel_launch(void* const* d_in, const int* in_sizes, int n_in,
                              void* d_out, int out_size, void* d_ws, size_t ws_size,
                              hipStream_t stream) {
    const float* x = (const float*)d_in[0];   // [16384, 4096] fp32
    const float* W = (const float*)d_in[1];   // [64, 4096] fp32
    float* out = (float*)d_out;               // weights [16384*64] then indices [16384*2]
    short* Wp  = (short*)d_ws;                // 1 MB packed W (bf16 hi/lo fragments)
    (void)in_sizes; (void)n_in; (void)ws_size; (void)out_size;

    hipLaunchKernelGGL(pack_w_kernel, dim3(DDIM / 32), dim3(256), 0, stream, W, Wp);
    hipLaunchKernelGGL(topk_gate_kernel, dim3(N_TOK / TM), dim3(512), 0, stream,
                       x, Wp, W, out);
}

// Round 7
// 502.602 us; speedup vs baseline: 1.0170x; 1.0170x over previous
//
#include <hip/hip_runtime.h>
#include <math.h>

#define N_TOK 16384
#define DDIM  4096
#define NEXP  64
#define TM    32             // tokens per block
#define WINF  256            // f32 columns staged per row per step (1 KB/row)
#define NSTEP (DDIM / WINF)  // 16 steps
#define LSTR  68             // LDS logit row stride
#define TAU   1e-3f          // near-tie refine threshold

typedef __attribute__((ext_vector_type(8))) short bf16x8;
typedef __attribute__((ext_vector_type(4))) float f32x4;

// Split 8 consecutive fp32 into hi/lo bf16 (truncation split: x = hi + lo + eps).
__device__ __forceinline__ void split8(f32x4 v0, f32x4 v1, bf16x8& hi, bf16x8& lo) {
    float f[8];
    *(f32x4*)&f[0] = v0;  *(f32x4*)&f[4] = v1;
    #pragma unroll
    for (int i = 0; i < 8; ++i) {
        unsigned u  = __float_as_uint(f[i]);
        unsigned uh = u & 0xFFFF0000u;
        float    rf = f[i] - __uint_as_float(uh);
        hi[i] = (short)(u >> 16);
        lo[i] = (short)(__float_as_uint(rf) >> 16);
    }
}

// ---------------- W pre-pack: fragment-ordered bf16 hi/lo (1 MB in d_ws) -----
// Wp[((c*4+t)*2+p)*512 + lane*8 .. +7] = split of W[t*16+(lane&15)][c*32+(lane>>4)*8 + 0..7]
__global__ __launch_bounds__(256) void pack_w_kernel(
    const float* __restrict__ W, short* __restrict__ Wp)
{
    const int c    = blockIdx.x;          // K chunk of 32
    const int tid  = threadIdx.x;
    const int t    = tid >> 6;
    const int lane = tid & 63;
    const int r16  = lane & 15;
    const int koct = lane >> 4;
    const float* src = W + (size_t)(t * 16 + r16) * DDIM + c * 32 + koct * 8;
    f32x4 b0 = *(const f32x4*)src;
    f32x4 b1 = *(const f32x4*)(src + 4);
    bf16x8 hi, lo;
    split8(b0, b1, hi, lo);
    short* d = Wp + ((size_t)(c * 4 + t) * 2) * 512 + lane * 8;
    *(bf16x8*)d         = hi;
    *(bf16x8*)(d + 512) = lo;
}

// ---------------- main kernel: reg-staged double buffer + K-phase rotation ---
// NEW vs R5: each block walks the 16 K-windows in rotated order, phase =
// (blockIdx>>3)&15, so the device-wide concurrent address set covers ALL
// window positions mod 16 KB (DRAM-channel / L2-bank coverage), instead of
// every block hammering the same aligned 1 KB window simultaneously.
__global__ __launch_bounds__(512, 4) void topk_gate_kernel(
    const float* __restrict__ x, const short* __restrict__ Wp,
    const float* __restrict__ W, float* __restrict__ out)
{
    __shared__ __align__(16) char sraw[73728];   // ring 64K; Lg 69.6K; +red 4K
    __shared__ int    top_i[TM * 2];
    __shared__ float  top_w[TM * 2];
    __shared__ int    nflag;
    __shared__ int    flist[TM];
    __shared__ double lgd[NEXP];
    __shared__ int    rbi[2];
    __shared__ float  rbw[2];

    const int tid  = threadIdx.x;
    const int lane = tid & 63;
    const int w    = tid >> 6;            // wave 0..7 (uniform role)
    const int block_tok = blockIdx.x * TM;
    const int phase = (blockIdx.x >> 3) & 15;   // K-window rotation (>>3: all 16
                                                // phases present on every XCD)
    const int r16  = lane & 15;
    const int koct = lane >> 4;
    const int m    = (r16 & 7) << 4;      // read-side XOR
    const int o0   = w * 128 + koct * 32; // this wave's chunk offset in window

    // staging: wave w owns local rows w*4 .. w*4+3 (16384 B global row stride)
    const char* xrow = (const char*)x
                     + (size_t)(block_tok + w * 4) * (DDIM * 4) + lane * 16;
    const int sw0 = (lane * 16) ^ ((((w * 4) + 0) & 7) << 4);
    const int sw1 = (lane * 16) ^ ((((w * 4) + 1) & 7) << 4);
    const int sw2 = (lane * 16) ^ ((((w * 4) + 2) & 7) << 4);
    const int sw3 = (lane * 16) ^ ((((w * 4) + 3) & 7) << 4);
    char* const wbase = sraw + (w * 4) * 1024;

    f32x4 rA0, rA1, rA2, rA3, rB0, rB1, rB2, rB3;

#define LOADR(a0, a1, a2, a3, S) do {                                        \
    const char* _s = xrow + (size_t)(S) * 1024;                              \
    a0 = *(const f32x4*)(_s);                                                \
    a1 = *(const f32x4*)(_s + 16384);                                        \
    a2 = *(const f32x4*)(_s + 32768);                                        \
    a3 = *(const f32x4*)(_s + 49152);                                        \
} while (0)

#define WRITER(a0, a1, a2, a3, B) do {                                       \
    char* _d = wbase + (B) * 32768;                                          \
    *(f32x4*)(_d +        sw0) = a0;                                         \
    *(f32x4*)(_d + 1024 + sw1) = a1;                                         \
    *(f32x4*)(_d + 2048 + sw2) = a2;                                         \
    *(f32x4*)(_d + 3072 + sw3) = a3;                                         \
} while (0)

    f32x4 acc[2][4];
    #pragma unroll
    for (int tt = 0; tt < 2; ++tt)
        #pragma unroll
        for (int t = 0; t < 4; ++t) acc[tt][t] = (f32x4){0.f, 0.f, 0.f, 0.f};

#define COMPUTE(B, S) do {                                                   \
    const char* _buf = sraw + (B) * 32768;                                   \
    const int _cg = (S) * 8 + w;                 /* global K chunk */        \
    bf16x8 ah[2], al[2];                                                     \
    _Pragma("unroll")                                                        \
    for (int tt = 0; tt < 2; ++tt) {                                         \
        const char* xb = _buf + ((tt * 16 + r16) << 10);                     \
        f32x4 a0 = *(const f32x4*)(xb + (o0 ^ m));                           \
        f32x4 a1 = *(const f32x4*)(xb + ((o0 + 16) ^ m));                    \
        split8(a0, a1, ah[tt], al[tt]);                                      \
    }                                                                        \
    _Pragma("unroll")                                                        \
    for (int t = 0; t < 4; ++t) {                                            \
        const short* wb = Wp + ((size_t)(_cg * 4 + t) * 2) * 512 + lane * 8; \
        bf16x8 bh = *(const bf16x8*)wb;                                      \
        bf16x8 bl = *(const bf16x8*)(wb + 512);                              \
        _Pragma("unroll")                                                    \
        for (int tt = 0; tt < 2; ++tt) {                                     \
            acc[tt][t] = __builtin_amdgcn_mfma_f32_16x16x32_bf16(ah[tt], bh, acc[tt][t], 0, 0, 0); \
            acc[tt][t] = __builtin_amdgcn_mfma_f32_16x16x32_bf16(ah[tt], bl, acc[tt][t], 0, 0, 0); \
            acc[tt][t] = __builtin_amdgcn_mfma_f32_16x16x32_bf16(al[tt], bh, acc[tt][t], 0, 0, 0); \
        }                                                                    \
    }                                                                        \
} while (0)

    // ---- 2-deep reg pipeline over 16 rotated windows, double-buffered LDS ----
    LOADR(rA0, rA1, rA2, rA3, (phase + 0) & 15);
    LOADR(rB0, rB1, rB2, rB3, (phase + 1) & 15);
    #pragma unroll 1
    for (int si = 0; si < NSTEP; si += 2) {
        WRITER(rA0, rA1, rA2, rA3, 0);          // compiler waits rA loads here
        __syncthreads();
        if (si + 2 < NSTEP) LOADR(rA0, rA1, rA2, rA3, (phase + si + 2) & 15);
        COMPUTE(0, (phase + si) & 15);
        __syncthreads();
        WRITER(rB0, rB1, rB2, rB3, 1);
        __syncthreads();
        if (si + 3 < NSTEP) LOADR(rB0, rB1, rB2, rB3, (phase + si + 3) & 15);
        COMPUTE(1, (phase + si + 1) & 15);
        __syncthreads();
    }
#undef LOADR
#undef WRITER
#undef COMPUTE

    // ---- epilogue: per-partition logits into LDS (ring dead) ----
    float* Lg = (float*)sraw;             // [8][32][LSTR]
    #pragma unroll
    for (int tt = 0; tt < 2; ++tt)
        #pragma unroll
        for (int t = 0; t < 4; ++t)
            #pragma unroll
            for (int r = 0; r < 4; ++r)
                Lg[(w * TM + tt * 16 + koct * 4 + r) * LSTR + t * 16 + r16] = acc[tt][t][r];
    if (tid == 0) nflag = 0;
    __syncthreads();

    // ---- combine 8 K-partitions: 512 threads x (1 token, 4 experts) ----
    {
        const int tok = tid >> 4;
        const int e4  = (tid & 15) * 4;
        float4 s0 = *(float4*)&Lg[(0 * TM + tok) * LSTR + e4];
        #pragma unroll
        for (int qq = 1; qq < 8; ++qq) {
            float4 v = *(float4*)&Lg[(qq * TM + tok) * LSTR + e4];
            s0.x += v.x; s0.y += v.y; s0.z += v.z; s0.w += v.w;
        }
        *(float4*)&Lg[tok * LSTR + e4] = s0;
    }
    __syncthreads();

    // ---- top-3 scan + 2-way softmax + near-tie flagging ----
    if (tid < TM) {
        float m1 = -INFINITY, m2 = -INFINITY, m3 = -INFINITY;
        int i1 = 0, i2 = 0;
        for (int e = 0; e < NEXP; ++e) {
            float v = Lg[tid * LSTR + e];
            if (v > m1)      { m3 = m2; m2 = m1; i2 = i1; m1 = v; i1 = e; }
            else if (v > m2) { m3 = m2; m2 = v; i2 = e; }
            else if (v > m3) { m3 = v; }
        }
        float d  = expf(m2 - m1);
        float rn = 1.0f / (1.0f + d);
        top_i[tid * 2 + 0] = i1;  top_i[tid * 2 + 1] = i2;
        top_w[tid * 2 + 0] = rn;  top_w[tid * 2 + 1] = d * rn;
        float2* oi = (float2*)(out + (size_t)N_TOK * NEXP);
        oi[block_tok + tid] = make_float2((float)i1, (float)i2);
        if ((m1 - m2 < TAU) || (m2 - m3 < TAU)) {
            int pp = atomicAdd(&nflag, 1);
            flist[pp] = tid;
        }
    }
    __syncthreads();

    // ---- dense weight scatter: 32 tokens x 64 experts = 512 float4 ----
    {
        float4* ow = (float4*)(out + (size_t)block_tok * NEXP);
        const int tok = tid >> 4;
        const int e4  = (tid & 15) * 4;
        int a1 = top_i[tok * 2], a2 = top_i[tok * 2 + 1];
        float v1 = top_w[tok * 2], v2 = top_w[tok * 2 + 1];
        float4 v; float* vp = (float*)&v;
        #pragma unroll
        for (int q = 0; q < 4; ++q) {
            int e = e4 + q;
            vp[q] = (e == a1) ? v1 : ((e == a2) ? v2 : 0.0f);
        }
        ow[tid] = v;
    }
    __syncthreads();

    // ---- in-block fp64 re-resolution of flagged tokens ----
    double* red = (double*)(sraw + 69632);   // past Lg
    const int fn = nflag;
    for (int f = 0; f < fn; ++f) {
        const int tok = block_tok + flist[f];
        {
            const int e = tid & 63, q = tid >> 6;   // q: 0..7
            const float* wr = W + (size_t)e * DDIM + q * (DDIM / 8);
            const float* xr = x + (size_t)tok * DDIM + q * (DDIM / 8);
            double pp = 0.0;
            for (int k = 0; k < DDIM / 8; k += 4) {
                float4 wv = *(const float4*)(wr + k);
                float4 xv = *(const float4*)(xr + k);
                pp += (double)xv.x * (double)wv.x;
                pp += (double)xv.y * (double)wv.y;
                pp += (double)xv.z * (double)wv.z;
                pp += (double)xv.w * (double)wv.w;
            }
            red[tid] = pp;
        }
        __syncthreads();
        if (tid < 64) {
            double s = 0.0;
            #pragma unroll
            for (int j = 0; j < 8; ++j) s += red[tid + 64 * j];
            lgd[tid] = s;
        }
        __syncthreads();

        if (tid == 0) {
            double m1 = -INFINITY, m2 = -INFINITY;
            int i1 = 0, i2 = 0;
            for (int ee = 0; ee < NEXP; ++ee) {
                double v = lgd[ee];
                if (v > m1)      { m2 = m1; i2 = i1; m1 = v; i1 = ee; }
                else if (v > m2) { m2 = v; i2 = ee; }
            }
            double d  = exp(m2 - m1);
            double rn = 1.0 / (1.0 + d);
            rbi[0] = i1; rbi[1] = i2;
            rbw[0] = (float)rn; rbw[1] = (float)(d * rn);
            float2* oi = (float2*)(out + (size_t)N_TOK * NEXP);
            oi[tok] = make_float2((float)i1, (float)i2);
        }
        __syncthreads();

        if (tid < 16) {
            float4 v = make_float4(0.f, 0.f, 0.f, 0.f);
            float* vp = (float*)&v;
            #pragma unroll
            for (int qq = 0; qq < 4; ++qq) {
                int ee = tid * 4 + qq;
                if (ee == rbi[0]) vp[qq] = rbw[0];
                else if (ee == rbi[1]) vp[qq] = rbw[1];
            }
            ((float4*)(out + (size_t)tok * NEXP))[tid] = v;
        }
        __syncthreads();
    }
}

extern "C" void kernel_launch(void* const* d_in, const int* in_sizes, int n_in,
                              void* d_out, int out_size, void* d_ws, size_t ws_size,
                              hipStream_t stream) {
    const float* x = (const float*)d_in[0];   // [16384, 4096] fp32
    const float* W = (const float*)d_in[1];   // [64, 4096] fp32
    float* out = (float*)d_out;               // weights [16384*64] then indices [16384*2]
    short* Wp  = (short*)d_ws;                // 1 MB packed W (bf16 hi/lo fragments)
    (void)in_sizes; (void)n_in; (void)ws_size; (void)out_size;

    hipLaunchKernelGGL(pack_w_kernel, dim3(DDIM / 32), dim3(256), 0, stream, W, Wp);
    hipLaunchKernelGGL(topk_gate_kernel, dim3(N_TOK / TM), dim3(512), 0, stream,
                       x, Wp, W, out);
}